// Round 6
// baseline (198.376 us; speedup 1.0000x reference)
//
#include <hip/hip_runtime.h>
#include <hip/hip_bf16.h>
#include <stdint.h>

// Problem constants: B=8, T=2048, C=1024 (n_embd), H=128 (head dim)
#define BB 8
#define TT 2048
#define CC 1024
#define HH 128
#define VTP 2112      // Vt row pitch (u16): 4224 B, breaks 4 KB set-aliasing

typedef __attribute__((ext_vector_type(8))) short bf16x8;
typedef __attribute__((ext_vector_type(8))) unsigned short u16x8;
typedef __attribute__((ext_vector_type(4))) float f32x4;
typedef __attribute__((ext_vector_type(8))) _Float16 h16x8;

static __device__ __forceinline__ unsigned short f2bf(float f) {
    union { float f; uint32_t u; } v; v.f = f;
    return (unsigned short)((v.u + 0x7fffu + ((v.u >> 16) & 1u)) >> 16);  // RNE
}

#define GLOBAL_AS __attribute__((address_space(1)))
#define LDS_AS    __attribute__((address_space(3)))
static __device__ __forceinline__ void async16(const void* g, void* l) {
    // global->LDS DMA, 16 B/lane; LDS dest = wave-uniform base + lane*16
    __builtin_amdgcn_global_load_lds((const GLOBAL_AS void*)g, (LDS_AS void*)l, 16, 0, 0);
}

// ---------------------------------------------------------------------------
// Kernel 0: W fp32 [k][n] -> bf16 Wb [3*128 n][1024 k]  (k-contiguous rows)
// ---------------------------------------------------------------------------
__global__ __launch_bounds__(256) void wconv(
    const float* __restrict__ Wq, const float* __restrict__ Wk,
    const float* __restrict__ Wv, unsigned short* __restrict__ Wb)
{
    int u = blockIdx.x * 256 + threadIdx.x;
    if (u >= 3 * 128 * 128) return;
    int kc = u & 127, n = (u >> 7) & 127, mat = u >> 14;
    const float* W = (mat == 0) ? Wq : (mat == 1) ? Wk : Wv;
    const float* s = W + (size_t)(kc * 8) * HH + n;
    u16x8 v;
    #pragma unroll
    for (int j = 0; j < 8; j++) v[j] = f2bf(s[(size_t)j * HH]);
    *(u16x8*)(Wb + ((size_t)mat * HH + n) * CC + kc * 8) = v;
}

// ---------------------------------------------------------------------------
// Kernel 1: fused QKV projection. BM=64, BN=384 (Q|K|V: x read ONCE), BK=64.
// 256 thr = 4 waves, each 32m x 192n => 48 MFMA per barrier per wave.
// x: fp32 global->reg prefetch (1 step ahead) -> f2bf -> As (pitch 72).
// W: async16 into XOR-swizzled Bs. grid = 256 blocks.
// ---------------------------------------------------------------------------
#define AS_U16 4608          // As: 64 rows * 72 pitch
#define BS_U16 4608          // Bs offset; 3072 slots * 8 u16 = 24576
#define EQ_OFF 0             // epilogue reuse: Q [64][136]
#define EK_OFF 8704          // K [64][136]
#define EV_OFF 17408         // V [128][72]
__global__ __launch_bounds__(256) void qkv_proj(
    const float* __restrict__ x, const unsigned short* __restrict__ Wb,
    unsigned short* __restrict__ Q, unsigned short* __restrict__ K,
    unsigned short* __restrict__ Vt)
{
    __shared__ __align__(16) unsigned short lds[29184];   // 58.4 KB

    const int m0  = blockIdx.x * 64;
    const int tid = threadIdx.x;
    const int lane = tid & 63;
    const int w    = tid >> 6;
    const int qd   = lane >> 4;
    const int ln   = lane & 15;
    const int wm   = w & 1;          // m half (32 rows)
    const int wn   = w >> 1;         // n half (192 cols)

    f32x4 acc[2][12];
    #pragma unroll
    for (int i = 0; i < 2; i++)
        #pragma unroll
        for (int j = 0; j < 12; j++) acc[i][j] = (f32x4){0.f,0.f,0.f,0.f};

    const int xr = tid >> 2;            // 0..63
    const int xg = (tid & 3) * 16;      // col base (floats / u16)

    // preload x regs for k0 = 0
    float4 xf[4];
    {
        const float* s = x + (size_t)(m0 + xr) * CC + xg;
        #pragma unroll
        for (int i = 0; i < 4; i++) xf[i] = ((const float4*)s)[i];
    }

    for (int k0 = 0; k0 < CC; k0 += 64) {
        // As write from regs (16 floats -> 2 u16x8)
        {
            u16x8 v0, v1;
            v0[0]=f2bf(xf[0].x); v0[1]=f2bf(xf[0].y); v0[2]=f2bf(xf[0].z); v0[3]=f2bf(xf[0].w);
            v0[4]=f2bf(xf[1].x); v0[5]=f2bf(xf[1].y); v0[6]=f2bf(xf[1].z); v0[7]=f2bf(xf[1].w);
            v1[0]=f2bf(xf[2].x); v1[1]=f2bf(xf[2].y); v1[2]=f2bf(xf[2].z); v1[3]=f2bf(xf[2].w);
            v1[4]=f2bf(xf[3].x); v1[5]=f2bf(xf[3].y); v1[6]=f2bf(xf[3].z); v1[7]=f2bf(xf[3].w);
            *(u16x8*)&lds[xr * 72 + xg]     = v0;
            *(u16x8*)&lds[xr * 72 + xg + 8] = v1;
        }
        // prefetch x for next step (latency overlaps MFMA phase / barrier)
        if (k0 + 64 < CC) {
            const float* s = x + (size_t)(m0 + xr) * CC + k0 + 64 + xg;
            #pragma unroll
            for (int i = 0; i < 4; i++) xf[i] = ((const float4*)s)[i];
        }
        // stage W: 384 rows x 64 k, async16 x12, XOR-swizzled chunk slots
        #pragma unroll
        for (int i = 0; i < 12; i++) {
            int sb = i * 256 + w * 64;           // wave-uniform slot base
            int slot = sb + lane;
            int row = slot >> 3, j = (slot & 7) ^ (row & 7);
            async16(Wb + (size_t)row * CC + k0 + j * 8, &lds[BS_U16 + sb * 8]);
        }
        __syncthreads();
        #pragma unroll
        for (int ks = 0; ks < 2; ks++) {
            bf16x8 a0 = *(const bf16x8*)&lds[(wm*32 + ln) * 72 + ks*32 + qd*8];
            bf16x8 a1 = *(const bf16x8*)&lds[(wm*32 + 16 + ln) * 72 + ks*32 + qd*8];
            #pragma unroll
            for (int nf = 0; nf < 12; nf++) {
                int row = wn * 192 + nf * 16 + ln;
                int ch  = (ks * 4 + qd) ^ (row & 7);
                bf16x8 b = *(const bf16x8*)&lds[BS_U16 + (row * 8 + ch) * 8];
                acc[0][nf] = __builtin_amdgcn_mfma_f32_16x16x32_bf16(a0, b, acc[0][nf], 0, 0, 0);
                acc[1][nf] = __builtin_amdgcn_mfma_f32_16x16x32_bf16(a1, b, acc[1][nf], 0, 0, 0);
            }
        }
        __syncthreads();
    }

    // ---- epilogue: acc -> LDS -> coalesced stores ----
    #pragma unroll
    for (int mf = 0; mf < 2; mf++)
        #pragma unroll
        for (int nf = 0; nf < 12; nf++) {
            int n = wn * 192 + nf * 16;          // 16-aligned, never crosses a matrix
            int mat = n >> 7, hb = n & 127;
            #pragma unroll
            for (int r = 0; r < 4; r++) {
                unsigned short v = f2bf(acc[mf][nf][r]);
                int mrow = wm*32 + mf*16 + qd*4 + r;     // 0..63
                if (mat < 2) lds[(mat ? EK_OFF : EQ_OFF) + mrow * 136 + hb + ln] = v;
                else         lds[EV_OFF + (hb + ln) * 72 + mrow] = v;
            }
        }
    __syncthreads();
    {
        int rr = tid >> 2, c0 = (tid & 3) * 32;
        #pragma unroll
        for (int i = 0; i < 4; i++) {
            u16x8 vq = *(const u16x8*)&lds[EQ_OFF + rr * 136 + c0 + i * 8];
            *(u16x8*)(Q + (size_t)(m0 + rr) * HH + c0 + i * 8) = vq;
            u16x8 vk = *(const u16x8*)&lds[EK_OFF + rr * 136 + c0 + i * 8];
            *(u16x8*)(K + (size_t)(m0 + rr) * HH + c0 + i * 8) = vk;
        }
    }
    {
        int bb = m0 >> 11, t0 = m0 & (TT - 1);
        int hh = tid >> 1, tf = (tid & 1) * 32;
        #pragma unroll
        for (int i = 0; i < 4; i++) {
            u16x8 vv = *(const u16x8*)&lds[EV_OFF + hh * 72 + tf + i * 8];
            *(u16x8*)(Vt + ((size_t)bb * HH + hh) * VTP + t0 + tf + i * 8) = vv;
        }
    }
}

// ---------------------------------------------------------------------------
// Kernel 2: flash attention (causal), no-max softmax, 128-key steps,
// key-split x4, NO in-loop barriers (per-wave independent; P round-trips
// through the wave's own LDS slice). End-only merge: l via shuffles,
// partial O in fp16 overlaid on Ps. grid = 1024 (8 b x 128 qt, long-first),
// 256 thr; LDS 17.7 KB; target 4 blocks/CU.
// ---------------------------------------------------------------------------
__global__ __launch_bounds__(256) void attn(
    const unsigned short* __restrict__ Q, const unsigned short* __restrict__ K,
    const unsigned short* __restrict__ Vt, float* __restrict__ out)
{
    __shared__ __align__(16) unsigned short Ps[4][16 * 136];   // 17.4 KB; reused as fp16 O
    __shared__ float Lp[4][16];

    const int tid  = threadIdx.x;
    const int lane = tid & 63;
    const int wave = tid >> 6;
    const int qd = lane >> 4;
    const int ln = lane & 15;

    const int bx = blockIdx.x;
    const int qt = 127 - (bx >> 3);              // long q-tiles first
    const int b  = bx & 7;
    const int qbase = qt * 16;
    const int nst = (16 * qt + 143) >> 7;        // ceil((16qt+16)/128)

    const unsigned short* Qb = Q  + (size_t)b * TT * HH;
    const unsigned short* Kb = K  + (size_t)b * TT * HH;
    const unsigned short* Vb = Vt + (size_t)b * HH * VTP;

    bf16x8 aq[4];
    #pragma unroll
    for (int c = 0; c < 4; c++)
        aq[c] = *(const bf16x8*)(Qb + (size_t)(qbase + ln) * HH + c * 32 + qd * 8);

    f32x4 O[8];
    float lsum[4];
    #pragma unroll
    for (int h = 0; h < 8; h++) O[h] = (f32x4){0.f,0.f,0.f,0.f};
    #pragma unroll
    for (int r = 0; r < 4; r++) lsum[r] = 0.f;

    const float sl   = 0.08838834764831843f * 1.4426950408889634f; // (1/sqrt128)*log2e
    const float M0L2 = 7.2134752044448f;                           // 5.0 * log2(e)
    unsigned short* ps = Ps[wave];

    for (int st = wave; st < nst; st += 4) {
        const int s0 = st * 128;
        // ---- S = Q K^T : 16 q x 128 keys (8 nt frags) ----
        #pragma unroll
        for (int nt = 0; nt < 8; nt++) {
            f32x4 s = (f32x4){0.f,0.f,0.f,0.f};
            const unsigned short* kp = Kb + (size_t)(s0 + nt*16 + ln) * HH + qd * 8;
            #pragma unroll
            for (int c = 0; c < 4; c++)
                s = __builtin_amdgcn_mfma_f32_16x16x32_bf16(aq[c], *(const bf16x8*)(kp + c*32), s, 0, 0, 0);
            // exp2 + causal mask + l accumulation + P store
            int col = s0 + nt * 16 + ln;
            #pragma unroll
            for (int r = 0; r < 4; r++) {
                int row = qbase + qd * 4 + r;
                float e = __builtin_amdgcn_exp2f(s[r] * sl - M0L2);
                e = (col <= row) ? e : 0.f;
                lsum[r] += e;
                ps[(qd*4 + r) * 136 + nt*16 + ln] = f2bf(e);
            }
        }
        // ---- P in A-layout: 4 k-chunks of 32 ----
        bf16x8 ap[4];
        #pragma unroll
        for (int kc = 0; kc < 4; kc++)
            ap[kc] = *(const bf16x8*)&ps[ln * 136 + kc*32 + qd*8];
        // ---- O += P V ----
        #pragma unroll
        for (int ht = 0; ht < 8; ht++) {
            const unsigned short* vp = Vb + (size_t)(ht*16 + ln) * VTP + s0 + qd*8;
            #pragma unroll
            for (int kc = 0; kc < 4; kc++)
                O[ht] = __builtin_amdgcn_mfma_f32_16x16x32_bf16(ap[kc], *(const bf16x8*)(vp + kc*32), O[ht], 0, 0, 0);
        }
    }

    // ---- l: one shuffle-tree per owned row, once ----
    #pragma unroll
    for (int r = 0; r < 4; r++) {
        float sum = lsum[r];
        #pragma unroll
        for (int off = 1; off < 16; off <<= 1)
            sum += __shfl_xor(sum, off, 64);
        if (ln == 0) Lp[wave][qd*4 + r] = sum;
    }
    // ---- partial O -> fp16, overlaid on this wave's Ps slice ----
    _Float16* osh = (_Float16*)Ps[wave];
    #pragma unroll
    for (int ht = 0; ht < 8; ht++)
        #pragma unroll
        for (int r = 0; r < 4; r++)
            osh[(qd*4 + r) * 136 + ht*16 + ln] = (_Float16)O[ht][r];
    __syncthreads();

    // ---- merge + write: thread -> (row, 8 h) ----
    {
        int row = tid >> 4, h0 = (tid & 15) * 8;
        float L = Lp[0][row] + Lp[1][row] + Lp[2][row] + Lp[3][row];
        float inv = 1.0f / L;
        float o[8];
        #pragma unroll
        for (int j = 0; j < 8; j++) o[j] = 0.f;
        #pragma unroll
        for (int wv = 0; wv < 4; wv++) {
            h16x8 hv = *(const h16x8*)&((const _Float16*)Ps[wv])[row * 136 + h0];
            #pragma unroll
            for (int j = 0; j < 8; j++) o[j] += (float)hv[j];
        }
        float* op = out + ((size_t)b * TT + qbase + row) * HH + h0;
        float4 v0 = {o[0]*inv, o[1]*inv, o[2]*inv, o[3]*inv};
        float4 v1 = {o[4]*inv, o[5]*inv, o[6]*inv, o[7]*inv};
        ((float4*)op)[0] = v0;
        ((float4*)op)[1] = v1;
    }
}

// ---------------------------------------------------------------------------
extern "C" void kernel_launch(void* const* d_in, const int* in_sizes, int n_in,
                              void* d_out, int out_size, void* d_ws, size_t ws_size,
                              hipStream_t stream) {
    const float* x  = (const float*)d_in[0];
    const float* Wq = (const float*)d_in[1];
    const float* Wk = (const float*)d_in[2];
    const float* Wv = (const float*)d_in[3];

    // workspace (u16): Wb [384][1024]; Q,K [16384][128]; Vt [8][128][VTP]
    unsigned short* Wb = (unsigned short*)d_ws;
    unsigned short* Qw = Wb + (size_t)3 * HH * CC;
    unsigned short* Kw = Qw + (size_t)BB * TT * HH;
    unsigned short* Vw = Kw + (size_t)BB * TT * HH;

    wconv<<<dim3(192), 256, 0, stream>>>(Wq, Wk, Wv, Wb);
    qkv_proj<<<dim3(256), 256, 0, stream>>>(x, Wb, Qw, Kw, Vw);
    attn<<<dim3(1024), 256, 0, stream>>>(Qw, Kw, Vw, (float*)d_out);
}

// Round 7
// 170.044 us; speedup vs baseline: 1.1666x; 1.1666x over previous
//
#include <hip/hip_runtime.h>
#include <hip/hip_bf16.h>
#include <stdint.h>

// Problem constants: B=8, T=2048, C=1024 (n_embd), H=128 (head dim)
#define BB 8
#define TT 2048
#define CC 1024
#define HH 128
#define VTP 2112      // Vt row pitch (u16): 4224 B, breaks 4 KB set-aliasing

typedef __attribute__((ext_vector_type(8))) short bf16x8;
typedef __attribute__((ext_vector_type(8))) unsigned short u16x8;
typedef __attribute__((ext_vector_type(4))) float f32x4;
typedef __attribute__((ext_vector_type(8))) _Float16 h16x8;

static __device__ __forceinline__ unsigned short f2bf(float f) {
    union { float f; uint32_t u; } v; v.f = f;
    return (unsigned short)((v.u + 0x7fffu + ((v.u >> 16) & 1u)) >> 16);  // RNE
}

#define GLOBAL_AS __attribute__((address_space(1)))
#define LDS_AS    __attribute__((address_space(3)))
static __device__ __forceinline__ void async16(const void* g, void* l) {
    // global->LDS DMA, 16 B/lane; LDS dest = wave-uniform base + lane*16
    __builtin_amdgcn_global_load_lds((const GLOBAL_AS void*)g, (LDS_AS void*)l, 16, 0, 0);
}

// ---------------------------------------------------------------------------
// Kernel 0: W fp32 [k][n] -> bf16 Wb [3*128 n][1024 k]  (k-contiguous rows)
// ---------------------------------------------------------------------------
__global__ __launch_bounds__(256) void wconv(
    const float* __restrict__ Wq, const float* __restrict__ Wk,
    const float* __restrict__ Wv, unsigned short* __restrict__ Wb)
{
    int u = blockIdx.x * 256 + threadIdx.x;
    if (u >= 3 * 128 * 128) return;
    int kc = u & 127, n = (u >> 7) & 127, mat = u >> 14;
    const float* W = (mat == 0) ? Wq : (mat == 1) ? Wk : Wv;
    const float* s = W + (size_t)(kc * 8) * HH + n;
    u16x8 v;
    #pragma unroll
    for (int j = 0; j < 8; j++) v[j] = f2bf(s[(size_t)j * HH]);
    *(u16x8*)(Wb + ((size_t)mat * HH + n) * CC + kc * 8) = v;
}

// ---------------------------------------------------------------------------
// Kernel 1 (unchanged from R6): fused QKV projection. BM=64, BN=384, BK=64,
// 4 waves each 32m x 192n (48 MFMA/barrier). x fp32 reg-prefetch -> As;
// W async16 -> XOR-swizzled Bs. grid = 256.
// ---------------------------------------------------------------------------
#define BS_U16 4608
#define EQ_OFF 0
#define EK_OFF 8704
#define EV_OFF 17408
__global__ __launch_bounds__(256) void qkv_proj(
    const float* __restrict__ x, const unsigned short* __restrict__ Wb,
    unsigned short* __restrict__ Q, unsigned short* __restrict__ K,
    unsigned short* __restrict__ Vt)
{
    __shared__ __align__(16) unsigned short lds[29184];   // 58.4 KB

    const int m0  = blockIdx.x * 64;
    const int tid = threadIdx.x;
    const int lane = tid & 63;
    const int w    = tid >> 6;
    const int qd   = lane >> 4;
    const int ln   = lane & 15;
    const int wm   = w & 1;
    const int wn   = w >> 1;

    f32x4 acc[2][12];
    #pragma unroll
    for (int i = 0; i < 2; i++)
        #pragma unroll
        for (int j = 0; j < 12; j++) acc[i][j] = (f32x4){0.f,0.f,0.f,0.f};

    const int xr = tid >> 2;
    const int xg = (tid & 3) * 16;

    float4 xf[4];
    {
        const float* s = x + (size_t)(m0 + xr) * CC + xg;
        #pragma unroll
        for (int i = 0; i < 4; i++) xf[i] = ((const float4*)s)[i];
    }

    for (int k0 = 0; k0 < CC; k0 += 64) {
        {
            u16x8 v0, v1;
            v0[0]=f2bf(xf[0].x); v0[1]=f2bf(xf[0].y); v0[2]=f2bf(xf[0].z); v0[3]=f2bf(xf[0].w);
            v0[4]=f2bf(xf[1].x); v0[5]=f2bf(xf[1].y); v0[6]=f2bf(xf[1].z); v0[7]=f2bf(xf[1].w);
            v1[0]=f2bf(xf[2].x); v1[1]=f2bf(xf[2].y); v1[2]=f2bf(xf[2].z); v1[3]=f2bf(xf[2].w);
            v1[4]=f2bf(xf[3].x); v1[5]=f2bf(xf[3].y); v1[6]=f2bf(xf[3].z); v1[7]=f2bf(xf[3].w);
            *(u16x8*)&lds[xr * 72 + xg]     = v0;
            *(u16x8*)&lds[xr * 72 + xg + 8] = v1;
        }
        if (k0 + 64 < CC) {
            const float* s = x + (size_t)(m0 + xr) * CC + k0 + 64 + xg;
            #pragma unroll
            for (int i = 0; i < 4; i++) xf[i] = ((const float4*)s)[i];
        }
        #pragma unroll
        for (int i = 0; i < 12; i++) {
            int sb = i * 256 + w * 64;
            int slot = sb + lane;
            int row = slot >> 3, j = (slot & 7) ^ (row & 7);
            async16(Wb + (size_t)row * CC + k0 + j * 8, &lds[BS_U16 + sb * 8]);
        }
        __syncthreads();
        #pragma unroll
        for (int ks = 0; ks < 2; ks++) {
            bf16x8 a0 = *(const bf16x8*)&lds[(wm*32 + ln) * 72 + ks*32 + qd*8];
            bf16x8 a1 = *(const bf16x8*)&lds[(wm*32 + 16 + ln) * 72 + ks*32 + qd*8];
            #pragma unroll
            for (int nf = 0; nf < 12; nf++) {
                int row = wn * 192 + nf * 16 + ln;
                int ch  = (ks * 4 + qd) ^ (row & 7);
                bf16x8 b = *(const bf16x8*)&lds[BS_U16 + (row * 8 + ch) * 8];
                acc[0][nf] = __builtin_amdgcn_mfma_f32_16x16x32_bf16(a0, b, acc[0][nf], 0, 0, 0);
                acc[1][nf] = __builtin_amdgcn_mfma_f32_16x16x32_bf16(a1, b, acc[1][nf], 0, 0, 0);
            }
        }
        __syncthreads();
    }

    #pragma unroll
    for (int mf = 0; mf < 2; mf++)
        #pragma unroll
        for (int nf = 0; nf < 12; nf++) {
            int n = wn * 192 + nf * 16;
            int mat = n >> 7, hb = n & 127;
            #pragma unroll
            for (int r = 0; r < 4; r++) {
                unsigned short v = f2bf(acc[mf][nf][r]);
                int mrow = wm*32 + mf*16 + qd*4 + r;
                if (mat < 2) lds[(mat ? EK_OFF : EQ_OFF) + mrow * 136 + hb + ln] = v;
                else         lds[EV_OFF + (hb + ln) * 72 + mrow] = v;
            }
        }
    __syncthreads();
    {
        int rr = tid >> 2, c0 = (tid & 3) * 32;
        #pragma unroll
        for (int i = 0; i < 4; i++) {
            u16x8 vq = *(const u16x8*)&lds[EQ_OFF + rr * 136 + c0 + i * 8];
            *(u16x8*)(Q + (size_t)(m0 + rr) * HH + c0 + i * 8) = vq;
            u16x8 vk = *(const u16x8*)&lds[EK_OFF + rr * 136 + c0 + i * 8];
            *(u16x8*)(K + (size_t)(m0 + rr) * HH + c0 + i * 8) = vk;
        }
    }
    {
        int bb = m0 >> 11, t0 = m0 & (TT - 1);
        int hh = tid >> 1, tf = (tid & 1) * 32;
        #pragma unroll
        for (int i = 0; i < 4; i++) {
            u16x8 vv = *(const u16x8*)&lds[EV_OFF + hh * 72 + tf + i * 8];
            *(u16x8*)(Vt + ((size_t)bb * HH + hh) * VTP + t0 + tf + i * 8) = vv;
        }
    }
}

// ---------------------------------------------------------------------------
// Kernel 2: flash attention (causal), no-max softmax. Block = 32 q-rows,
// 64-key steps, double-buffered cooperative async16 K/V staging with ONE
// barrier per step (asyncs issued after the barrier -> full compute phase
// to complete). Wave = (qgrp: 16 q-rows) x (khalf: 32 keys); per-wave P
// round-trip through private LDS (no sharing); 2-way O/l merge at end only.
// XOR chunk swizzle on Ks/Vs (async16-compatible, 2-way conflict = free).
// grid = 512 (8 b x 64 qt, long-first), 256 thr, LDS 69 KB -> 2 blocks/CU.
// ---------------------------------------------------------------------------
__global__ __launch_bounds__(256) void attn(
    const unsigned short* __restrict__ Q, const unsigned short* __restrict__ K,
    const unsigned short* __restrict__ Vt, float* __restrict__ out)
{
    __shared__ __align__(16) unsigned short Ks[2][64 * 128];  // 32 KB, swizzled chunks
    __shared__ __align__(16) unsigned short Vs[2][128 * 64];  // 32 KB, swizzled chunks
    __shared__ __align__(16) unsigned short Ps[4][16 * 40];   // 5 KB, per-wave P
    __shared__ float Lp[4][16];

    const int tid  = threadIdx.x;
    const int lane = tid & 63;
    const int wave = tid >> 6;
    const int qd = lane >> 4;
    const int ln = lane & 15;
    const int qgrp  = wave >> 1;          // 0: q rows 0-15, 1: rows 16-31
    const int khalf = wave & 1;           // key half within the 64-key step

    const int bx = blockIdx.x;
    const int b  = bx & 7;
    const int qt = 63 - (bx >> 3);        // longest q-tiles dispatched first
    const int qbase = qt * 32 + qgrp * 16;
    const int nst = (qt + 2) >> 1;        // 64-key steps; nst*64 <= 2048 always

    const unsigned short* Qb = Q  + (size_t)b * TT * HH;
    const unsigned short* Kb = K  + (size_t)b * TT * HH;
    const unsigned short* Vb = Vt + (size_t)b * HH * VTP;

    bf16x8 aq[4];
    #pragma unroll
    for (int c = 0; c < 4; c++)
        aq[c] = *(const bf16x8*)(Qb + (size_t)(qbase + ln) * HH + c * 32 + qd * 8);

    f32x4 O[8];
    float lsum[4];
    #pragma unroll
    for (int h = 0; h < 8; h++) O[h] = (f32x4){0.f,0.f,0.f,0.f};
    #pragma unroll
    for (int r = 0; r < 4; r++) lsum[r] = 0.f;

    const float sl   = 0.08838834764831843f * 1.4426950408889634f; // (1/sqrt128)*log2e
    const float M0L2 = 7.2134752044448f;                           // 5.0*log2(e)
    unsigned short* ps = Ps[wave];

    // ---- staging: K 64 rows x 16 chunks (swizzle ^row&15); V 128 x 8 (^row&7) ----
    #define STAGE(S0, BUF)                                                          \
        do {                                                                        \
            _Pragma("unroll")                                                       \
            for (int i = 0; i < 4; i++) {                                           \
                int sb = i * 256 + wave * 64;                                       \
                int slot = sb + lane;                                               \
                int row = slot >> 4, jj = (slot & 15) ^ (row & 15);                 \
                async16(Kb + (size_t)((S0) + row) * HH + jj * 8, &Ks[BUF][sb * 8]); \
            }                                                                       \
            _Pragma("unroll")                                                       \
            for (int i = 0; i < 4; i++) {                                           \
                int sb = i * 256 + wave * 64;                                       \
                int slot = sb + lane;                                               \
                int row = slot >> 3, jj = (slot & 7) ^ (row & 7);                   \
                async16(Vb + (size_t)row * VTP + (S0) + jj * 8, &Vs[BUF][sb * 8]);  \
            }                                                                       \
        } while (0)

    STAGE(0, 0);
    for (int st = 0; st < nst; st++) {
        __syncthreads();                       // drains prev-step asyncs, syncs waves
        const int buf = st & 1;
        if (st + 1 < nst) STAGE((st + 1) * 64, buf ^ 1);
        const int s0 = st * 64;

        // ---- S = Q K^T : 16 q x 32 keys (this wave's half) ----
        f32x4 s[2] = {(f32x4){0.f,0.f,0.f,0.f}, (f32x4){0.f,0.f,0.f,0.f}};
        #pragma unroll
        for (int nt = 0; nt < 2; nt++) {
            int krow = khalf * 32 + nt * 16;   // +ln = key within step
            #pragma unroll
            for (int c = 0; c < 4; c++) {
                bf16x8 bk = *(const bf16x8*)&Ks[buf][(krow + ln) * 128 + ((c*4 + qd) ^ ln) * 8];
                s[nt] = __builtin_amdgcn_mfma_f32_16x16x32_bf16(aq[c], bk, s[nt], 0, 0, 0);
            }
        }
        // ---- exp2 + causal mask; per-lane l; P -> private LDS (pitch 40) ----
        #pragma unroll
        for (int nt = 0; nt < 2; nt++) {
            int col = s0 + khalf * 32 + nt * 16 + ln;
            #pragma unroll
            for (int r = 0; r < 4; r++) {
                int row = qbase + qd * 4 + r;
                float e = __builtin_amdgcn_exp2f(s[nt][r] * sl - M0L2);
                e = (col <= row) ? e : 0.f;
                lsum[r] += e;
                ps[(qd*4 + r) * 40 + nt*16 + ln] = f2bf(e);
            }
        }
        // ---- P in A-layout (own slice; same-wave DS is in-order) ----
        bf16x8 ap = *(const bf16x8*)&ps[ln * 40 + qd * 8];
        // ---- O += P V over this wave's 32 keys, all 128 h ----
        #pragma unroll
        for (int ht = 0; ht < 8; ht++) {
            int vrow = ht * 16 + ln;
            bf16x8 bv = *(const bf16x8*)&Vs[buf][vrow * 64 + ((khalf*4 + qd) ^ (vrow & 7)) * 8];
            O[ht] = __builtin_amdgcn_mfma_f32_16x16x32_bf16(ap, bv, O[ht], 0, 0, 0);
        }
    }

    // ---- end: l reduce over ln lanes; O (fp16) into merge buffer on Ks ----
    __syncthreads();
    #pragma unroll
    for (int r = 0; r < 4; r++) {
        float sum = lsum[r];
        #pragma unroll
        for (int off = 1; off < 16; off <<= 1)
            sum += __shfl_xor(sum, off, 64);
        if (ln == 0) Lp[wave][qd*4 + r] = sum;
    }
    _Float16* om = (_Float16*)&Ks[0][0] + (size_t)wave * 16 * 128;
    #pragma unroll
    for (int ht = 0; ht < 8; ht++)
        #pragma unroll
        for (int r = 0; r < 4; r++)
            om[(qd*4 + r) * 128 + ht*16 + ln] = (_Float16)O[ht][r];
    __syncthreads();

    // ---- 2-way merge (key halves) + write ----
    {
        int row = tid >> 3, h0 = (tid & 7) * 16;   // 32 rows x 8 thr
        int g = row >> 4, q = row & 15;
        float L = Lp[2*g][q] + Lp[2*g + 1][q];
        float inv = 1.0f / L;
        const _Float16* p0 = (const _Float16*)&Ks[0][0] + (size_t)(2*g) * 2048 + q * 128 + h0;
        const _Float16* p1 = p0 + 2048;
        float* op = out + ((size_t)b * TT + qt * 32 + row) * HH + h0;
        #pragma unroll
        for (int i = 0; i < 4; i++) {
            float4 v;
            v.x = ((float)p0[i*4+0] + (float)p1[i*4+0]) * inv;
            v.y = ((float)p0[i*4+1] + (float)p1[i*4+1]) * inv;
            v.z = ((float)p0[i*4+2] + (float)p1[i*4+2]) * inv;
            v.w = ((float)p0[i*4+3] + (float)p1[i*4+3]) * inv;
            ((float4*)op)[i] = v;
        }
    }
    #undef STAGE
}

// ---------------------------------------------------------------------------
extern "C" void kernel_launch(void* const* d_in, const int* in_sizes, int n_in,
                              void* d_out, int out_size, void* d_ws, size_t ws_size,
                              hipStream_t stream) {
    const float* x  = (const float*)d_in[0];
    const float* Wq = (const float*)d_in[1];
    const float* Wk = (const float*)d_in[2];
    const float* Wv = (const float*)d_in[3];

    // workspace (u16): Wb [384][1024]; Q,K [16384][128]; Vt [8][128][VTP]
    unsigned short* Wb = (unsigned short*)d_ws;
    unsigned short* Qw = Wb + (size_t)3 * HH * CC;
    unsigned short* Kw = Qw + (size_t)BB * TT * HH;
    unsigned short* Vw = Kw + (size_t)BB * TT * HH;

    wconv<<<dim3(192), 256, 0, stream>>>(Wq, Wk, Wv, Wb);
    qkv_proj<<<dim3(256), 256, 0, stream>>>(x, Wb, Qw, Kw, Vw);
    attn<<<dim3(512), 256, 0, stream>>>(Qw, Kw, Vw, (float*)d_out);
}